// Round 8
// baseline (547.738 us; speedup 1.0000x reference)
//
#include <hip/hip_runtime.h>

typedef unsigned short u16;
typedef unsigned int   u32;
typedef __attribute__((ext_vector_type(8))) short short8;
typedef __attribute__((ext_vector_type(4))) float f32x4;

#define NN   2024
#define NB   128
#define HID  128
#define MTOT (NN*NB)      // 259072
#define RPB  256
#define NPB  (MTOT/RPB)   // 1012 = 8*126 + 4

__device__ __forceinline__ float bflo(u32 w){ union{u32 u; float f;}c; c.u=w<<16;        return c.f; }
__device__ __forceinline__ float bfhi(u32 w){ union{u32 u; float f;}c; c.u=w&0xffff0000u; return c.f; }
__device__ __forceinline__ float bf2f(u16 h){ union{u32 u; float f;}c; c.u=((u32)h)<<16; return c.f; }
__device__ __forceinline__ u16 f2bf(float f){ union{float f; u32 u;}c; c.f=f; return (u16)((c.u+0x7fffu+((c.u>>16)&1u))>>16); }
__device__ __forceinline__ u32 cvtpk(float lo, float hi){
  u32 r; asm("v_cvt_pk_bf16_f32 %0, %1, %2" : "=v"(r) : "v"(lo), "v"(hi)); return r;
}
__device__ __forceinline__ f32x4 mfma16(short8 a, short8 b, f32x4 c){
  return __builtin_amdgcn_mfma_f32_16x16x32_bf16(a,b,c,0,0,0);
}
__device__ __forceinline__ void glds16(const void* g, void* l){
  __builtin_amdgcn_global_load_lds((const __attribute__((address_space(1))) void*)g,
                                   (__attribute__((address_space(3))) void*)l, 16, 0, 0);
}
__device__ __forceinline__ u32 agg1(u32 a, u32 b, u32 c, u32 d,
                                    float w0, float w1, float w2, float w3){
  float lo = w0*bflo(a); lo=fmaf(w1,bflo(b),lo); lo=fmaf(w2,bflo(c),lo); lo=fmaf(w3,bflo(d),lo);
  float hi = w0*bfhi(a); hi=fmaf(w1,bfhi(b),hi); hi=fmaf(w2,bfhi(c),hi); hi=fmaf(w3,bfhi(d),hi);
  return cvtpk(lo, hi);
}

// ===== pass A: a[r] = weighted-mean of neighbor h rows (bf16), pure streaming =====
__global__ __launch_bounds__(256, 4)
void aggA_k(const u16* __restrict__ h, u16* __restrict__ a)
{
  const int t = threadIdx.x;
  const int row = blockIdx.x*128 + (t >> 1);
  const int hf = t & 1;
  const int nd = row % NN;
  const int v0 = (nd >= 45), v1 = (nd <= NN-46), v2 = (nd >= 1), v3 = (nd <= NN-2);
  const int cnt = v0+v1+v2+v3;
  const float inv = (cnt==4) ? 0.25f : ((cnt==3) ? (1.f/3.f) : 0.5f);
  const float w0 = v0?inv:0.f, w1 = v1?inv:0.f, w2 = v2?inv:0.f, w3 = v3?inv:0.f;

  const u16* p0 = h + (u32)(v0 ? row-45 : row)*128u + hf*64;
  const u16* p1 = h + (u32)(v1 ? row+45 : row)*128u + hf*64;
  const u16* p2 = h + (u32)(v2 ? row-1  : row)*128u + hf*64;
  const u16* p3 = h + (u32)(v3 ? row+1  : row)*128u + hf*64;
  u16* dst = a + (u32)row*128u + hf*64;

#pragma unroll
  for (int c = 0; c < 8; ++c){
    union{ uint4 v; u32 u[4]; } b0, b1, b2, b3, o;
    b0.v = *(const uint4*)(p0 + c*8);
    b1.v = *(const uint4*)(p1 + c*8);
    b2.v = *(const uint4*)(p2 + c*8);
    b3.v = *(const uint4*)(p3 + c*8);
#pragma unroll
    for (int p = 0; p < 4; ++p)
      o.u[p] = agg1(b0.u[p], b1.u[p], b2.u[p], b3.u[p], w0, w1, w2, w3);
    *(uint4*)(dst + c*8) = o.v;
  }
}

// ===== pass B: h'[r] = LN(relu(h[r]@W0 + a[r]@W1 + b))*g + beta, IN PLACE =====
// 1012 blocks x 512 thr (8 waves, 4 row-groups x 2 col-halves), 256 rows/block.
// W (both chunks, 64KB) in LDS staged once; K-loop barrier-free (h,a per-lane global).
__global__ __launch_bounds__(512, 2)
void layerB_k(u16* __restrict__ h, const u16* __restrict__ a,
              const u16* __restrict__ Wt, const float* __restrict__ bias,
              const float* __restrict__ lng, const float* __restrict__ lnb)
{
  __shared__ __align__(16) char Wl[65536];     // [128 col][256 k]*2B, 512B rows, XOR-swz
  __shared__ __align__(16) float2 red[256][2]; // 4KB LN partials
  const int t  = threadIdx.x;
  const int l  = t & 63;
  const int wv = t >> 6;
  const int wr = wv >> 1, wc = wv & 1;
  const int cB = l & 15, rg = l >> 4;

  // bijective XCD swizzle: 1012 = 8*126 + 4
  const int orig = blockIdx.x;
  const int xcd = orig & 7, bx = orig >> 3;
  const int m0 = ((xcd < 4 ? xcd*127 : 508 + (xcd-4)*126) + bx) * RPB;

  // ---- stage W once (R6-proven pattern): LDS[col][b] = Wt[col][b ^ ((col&7)<<4)] ----
#pragma unroll
  for (int i = 0; i < 8; ++i){
    const int slot = wv*8 + i;                  // 64 slots x 1KB
    const int col  = slot*2 + (l >> 5);
    const u32 kb   = ((u32)((l & 31)*16)) ^ ((u32)((col & 7) << 4));
    glds16((const char*)Wt + (u32)col*512 + kb, Wl + (u32)slot*1024);
  }

  f32x4 acc[4][4];
#pragma unroll
  for (int m = 0; m < 4; ++m)
#pragma unroll
    for (int j = 0; j < 4; ++j)
      acc[m][j] = (f32x4){0.f,0.f,0.f,0.f};

  const u32 kswz = ((u32)(cB & 7)) << 4;
  const char* wp[4];
#pragma unroll
  for (int j = 0; j < 4; ++j)
    wp[j] = Wl + (u32)(64*wc + 16*j + cB)*512;
  const char* sp = (const char*)h + (u32)(m0 + 64*wr + cB)*256u + (u32)rg*16u;
  const char* ap = (const char*)a + (u32)(m0 + 64*wr + cB)*256u + (u32)rg*16u;

  __syncthreads();   // B1: W resident

  // ---- barrier-free K-loop: self chunk (k 0..127) ----
#pragma unroll
  for (int ks = 0; ks < 4; ++ks){
    const u32 kb = (u32)ks*64u + (u32)rg*16u;
    const u32 kx = kb ^ kswz;
    short8 wf[4];
#pragma unroll
    for (int j = 0; j < 4; ++j) wf[j] = *(const short8*)(wp[j] + kx);
#pragma unroll
    for (int m = 0; m < 4; ++m){
      short8 s = *(const short8*)(sp + m*4096 + ks*64);
#pragma unroll
      for (int j = 0; j < 4; ++j) acc[m][j] = mfma16(s, wf[j], acc[m][j]);
    }
  }
  // ---- agg chunk (k 128..255) ----
#pragma unroll
  for (int ks = 0; ks < 4; ++ks){
    const u32 kb = (u32)ks*64u + (u32)rg*16u;
    const u32 kx = (256u + kb) ^ kswz;
    short8 wf[4];
#pragma unroll
    for (int j = 0; j < 4; ++j) wf[j] = *(const short8*)(wp[j] + kx);
#pragma unroll
    for (int m = 0; m < 4; ++m){
      short8 v = *(const short8*)(ap + m*4096 + ks*64);
#pragma unroll
      for (int j = 0; j < 4; ++j) acc[m][j] = mfma16(v, wf[j], acc[m][j]);
    }
  }

  // ---- epilogue: bias + relu + LN partials ----
  float b4[4], g4[4], bt4[4];
#pragma unroll
  for (int j = 0; j < 4; ++j){
    const int col = 64*wc + 16*j + cB;
    b4[j] = bias[col]; g4[j] = lng[col]; bt4[j] = lnb[col];
  }
#pragma unroll
  for (int m = 0; m < 4; ++m){
#pragma unroll
    for (int rr = 0; rr < 4; ++rr){
      float s1 = 0.f, s2 = 0.f;
#pragma unroll
      for (int j = 0; j < 4; ++j){
        float y = fmaxf(acc[m][j][rr] + b4[j], 0.f);
        acc[m][j][rr] = y;
        s1 += y; s2 = fmaf(y, y, s2);
      }
      s1 += __shfl_xor(s1,1); s1 += __shfl_xor(s1,2);
      s1 += __shfl_xor(s1,4); s1 += __shfl_xor(s1,8);
      s2 += __shfl_xor(s2,1); s2 += __shfl_xor(s2,2);
      s2 += __shfl_xor(s2,4); s2 += __shfl_xor(s2,8);
      if (cB == 0) red[64*wr + 16*m + 4*rg + rr][wc] = make_float2(s1, s2);
    }
  }
  __syncthreads();   // B2: red ready; all W reads done -> Wl reusable as trB

  char* trB = Wl;    // 256 rows x 256B
#pragma unroll
  for (int m = 0; m < 4; ++m){
#pragma unroll
    for (int rr = 0; rr < 4; ++rr){
      const int rl = 64*wr + 16*m + 4*rg + rr;
      const float2 A = red[rl][0], B = red[rl][1];
      const float s1 = A.x + B.x, s2 = A.y + B.y;
      const float mu = s1 * (1.f/128.f);
      const float va = s2 * (1.f/128.f) - mu*mu;
      const float rs = rsqrtf(va + 1e-5f);
      const u32 sw = ((u32)(rl & 7)) << 4;
      char* rowp = trB + (u32)rl*256;
#pragma unroll
      for (int j = 0; j < 4; ++j){
        const float y = fmaf((acc[m][j][rr]-mu)*rs, g4[j], bt4[j]);
        const float p = __shfl_xor(y, 1);
        const u32 pk = (cB & 1) ? cvtpk(p, y) : cvtpk(y, p);
        const u32 off = ((u32)(128*wc + 32*j + 2*(cB & ~1))) ^ sw;
        *(u32*)(rowp + off) = pk;
      }
    }
  }
  __syncthreads();   // B3: transpose ready

  // ---- coalesced in-place store (h rows fully consumed before B2) ----
  const int r = t >> 1, q = t & 1;
  const u32 sw2 = ((u32)(r & 7)) << 4;
  u16* dst = h + (size_t)(m0 + r)*HID + q*64;
  const char* srow = trB + (u32)r*256;
#pragma unroll
  for (int i = 0; i < 8; ++i)
    *(short8*)(dst + i*8) = *(const short8*)(srow + (((u32)(q*128 + i*16)) ^ sw2));
}

// ===== layer 1 (rank-1 shortcut) =====
__global__ __launch_bounds__(256, 4)
void l1_k(const float* __restrict__ x, const float* __restrict__ uvec,
          const float* __restrict__ lng, const float* __restrict__ lnb,
          u16* __restrict__ hout)
{
  __shared__ float su[384];
  __shared__ float sg[128], sb[128];
  const int t = threadIdx.x;
  const int m0 = ((blockIdx.x & 7)*253 + (blockIdx.x >> 3)) * 128;
  for (int i = t; i < 384; i += 256) su[i] = uvec[i];
  if (t < 128){ sg[t] = lng[t]; sb[t] = lnb[t]; }
  __syncthreads();

  const int r = t >> 1, hf = t & 1;
  const int grow = m0 + r;
  const int nd = grow % NN;
  const int v0 = (nd >= 45), v1 = (nd <= NN-46), v2 = (nd >= 1), v3 = (nd <= NN-2);
  const int cnt = v0+v1+v2+v3;
  const float inv = (cnt==4) ? 0.25f : ((cnt==3) ? (1.f/3.f) : 0.5f);
  const float xv = x[grow];
  float mx = 0.f;
  if (v0) mx += x[grow-45];
  if (v1) mx += x[grow+45];
  if (v2) mx += x[grow-1];
  if (v3) mx += x[grow+1];
  mx *= inv;

  const int fb = hf*64;
  float4 yv[16];
  float s1 = 0.f, s2 = 0.f;
#pragma unroll
  for (int i = 0; i < 16; ++i){
    const float4 aa = *(const float4*)(su + fb + i*4);
    const float4 bb = *(const float4*)(su + 128 + fb + i*4);
    const float4 cc = *(const float4*)(su + 256 + fb + i*4);
    float4 y;
    y.x = fmaxf(fmaf(xv, aa.x, fmaf(mx, bb.x, cc.x)), 0.f);
    y.y = fmaxf(fmaf(xv, aa.y, fmaf(mx, bb.y, cc.y)), 0.f);
    y.z = fmaxf(fmaf(xv, aa.z, fmaf(mx, bb.z, cc.z)), 0.f);
    y.w = fmaxf(fmaf(xv, aa.w, fmaf(mx, bb.w, cc.w)), 0.f);
    yv[i] = y;
    s1 += y.x + y.y + y.z + y.w;
    s2 = fmaf(y.x,y.x, fmaf(y.y,y.y, fmaf(y.z,y.z, fmaf(y.w,y.w, s2))));
  }
  s1 += __shfl_xor(s1, 1);
  s2 += __shfl_xor(s2, 1);
  const float muv = s1 * (1.f/128.f);
  const float var = s2 * (1.f/128.f) - muv*muv;
  const float rsv = rsqrtf(var + 1e-5f);

  u16* dst = hout + (size_t)grow*HID + fb;
#pragma unroll
  for (int i = 0; i < 8; ++i){
    const float4 ya = yv[2*i], yb = yv[2*i+1];
    const float4 ga = *(const float4*)(sg + fb + i*8);
    const float4 gb2 = *(const float4*)(sg + fb + i*8 + 4);
    const float4 ba = *(const float4*)(sb + fb + i*8);
    const float4 bb = *(const float4*)(sb + fb + i*8 + 4);
    u32 o0 = cvtpk(fmaf((ya.x-muv)*rsv, ga.x, ba.x), fmaf((ya.y-muv)*rsv, ga.y, ba.y));
    u32 o1 = cvtpk(fmaf((ya.z-muv)*rsv, ga.z, ba.z), fmaf((ya.w-muv)*rsv, ga.w, ba.w));
    u32 o2 = cvtpk(fmaf((yb.x-muv)*rsv, gb2.x, bb.x), fmaf((yb.y-muv)*rsv, gb2.y, bb.y));
    u32 o3 = cvtpk(fmaf((yb.z-muv)*rsv, gb2.z, bb.z), fmaf((yb.w-muv)*rsv, gb2.w, bb.w));
    uint4 pk = make_uint4(o0, o1, o2, o3);
    *(uint4*)(dst + i*8) = pk;
  }
}

// Transpose gnn_W [4][256k][128j] f32 -> Wt [4][128j][256k] bf16
__global__ void prep_k(const float* __restrict__ gw, u16* __restrict__ Wt){
  const int idx = blockIdx.x*256 + threadIdx.x;   // 131072
  const int lay = idx >> 15;
  const int r   = idx & 32767;
  const int j   = r >> 8;
  const int k   = r & 255;
  Wt[idx] = f2bf(gw[lay*32768 + k*128 + j]);
}

// u0 = We@W0_l0, u1 = We@W1_l0, c = be@(W0+W1) + b_l0
__global__ void prep2_k(const float* __restrict__ We, const float* __restrict__ be,
                        const float* __restrict__ gW, const float* __restrict__ gb,
                        float* __restrict__ uvec){
  const int f = threadIdx.x;  // 128
  float u0 = 0.f, u1 = 0.f, c = 0.f;
  for (int k = 0; k < 128; ++k){
    const float a = gW[k*128 + f];
    const float b = gW[(128+k)*128 + f];
    u0 = fmaf(We[k], a, u0);
    u1 = fmaf(We[k], b, u1);
    c  = fmaf(be[k], a + b, c);
  }
  uvec[f] = u0; uvec[128+f] = u1; uvec[256+f] = c + gb[f];
}

// ===== graph mean + heads =====
__global__ void mean1_k(const u16* __restrict__ h, float* __restrict__ partial){
  __shared__ float red[16][16][8];
  const int blk = blockIdx.x;                     // 1024 = 128 b x 8 s
  const int b = blk >> 3, s = blk & 7;
  const int t = threadIdx.x;
  const int cg = t & 15, q = t >> 4;
  const int nbeg = s*253, nend = nbeg + 253;
  float a[8] = {0.f,0.f,0.f,0.f,0.f,0.f,0.f,0.f};
  const u16* hb = h + (size_t)b * NN * HID;
  for (int n = nbeg + q; n < nend; n += 16){
    short8 v = *(const short8*)(hb + (size_t)n*HID + cg*8);
#pragma unroll
    for (int i = 0; i < 8; ++i) a[i] += bf2f((u16)v[i]);
  }
#pragma unroll
  for (int i = 0; i < 8; ++i) red[q][cg][i] = a[i];
  __syncthreads();
  if (t < 128){
    const int cc = t >> 3, i = t & 7;
    float v = 0.f;
#pragma unroll
    for (int qq = 0; qq < 16; ++qq) v += red[qq][cc][i];
    partial[((size_t)b*8 + s)*128 + t] = v;
  }
}

__global__ void mean2_k(const float* __restrict__ partial, float* __restrict__ gr){
  const int idx = blockIdx.x*256 + threadIdx.x;   // 16384
  const int b = idx >> 7, c = idx & 127;
  float a = 0.f;
#pragma unroll
  for (int s = 0; s < 8; ++s) a += partial[((size_t)b*8 + s)*128 + c];
  gr[idx] = a * (1.0f / 2024.0f);
}

__global__ void head1_k(const float* __restrict__ gr, const float* __restrict__ W1,
                        const float* __restrict__ b1, float* __restrict__ hid){
  const int idx = blockIdx.x*256 + threadIdx.x;   // 16384
  const int b = idx >> 7, j = idx & 127;
  const float* g = gr + b*128;
  float a = b1[j];
  for (int k = 0; k < 128; ++k) a = fmaf(g[k], W1[k*128 + j], a);
  hid[idx] = fmaxf(a, 0.f);
}

__global__ void head2_k(const float* __restrict__ hid, const float* __restrict__ W2,
                        const float* __restrict__ b2, float* __restrict__ out){
  const int t = threadIdx.x;                      // 256 = 128 b x 2 o
  const int b = t >> 1, o = t & 1;
  const float* hh = hid + b*128;
  float a = b2[o];
  for (int k = 0; k < 128; ++k) a = fmaf(hh[k], W2[k*2 + o], a);
  out[t] = a;
}

extern "C" void kernel_launch(void* const* d_in, const int* in_sizes, int n_in,
                              void* d_out, int out_size, void* d_ws, size_t ws_size,
                              hipStream_t stream){
  const float* x  = (const float*)d_in[0];
  const float* We = (const float*)d_in[1];
  const float* be = (const float*)d_in[2];
  const float* gW = (const float*)d_in[3];
  const float* gb = (const float*)d_in[4];
  const float* lg = (const float*)d_in[5];
  const float* lb = (const float*)d_in[6];
  const float* W1 = (const float*)d_in[7];
  const float* b1 = (const float*)d_in[8];
  const float* W2 = (const float*)d_in[9];
  const float* b2 = (const float*)d_in[10];
  float* out = (float*)d_out;

  char* w = (char*)d_ws;
  const size_t HB = (size_t)MTOT * HID * 2;       // 66,322,432 B
  u16*   h    = (u16*)w;                          // in-place h across layers
  u16*   a    = (u16*)(w + HB);                   // agg buffer (reused per layer)
  u16*   Wt   = (u16*)(w + 2*HB);                 // 262,144 B
  float* uvec = (float*)(w + 2*HB + 262144);      // 4,096 B slot
  float* gr   = (float*)(w + 2*HB + 266240);      // 65,536 B
  float* hid  = (float*)(w + 2*HB + 331776);      // 65,536 B
  float* partial = (float*)(w + HB);              // overlays a (dead after last layerB)

  prep2_k<<<1, 128, 0, stream>>>(We, be, gW, gb, uvec);
  prep_k<<<512, 256, 0, stream>>>(gW, Wt);
  l1_k<<<MTOT/128, 256, 0, stream>>>(x, uvec, lg, lb, h);

  // layers 2..4: agg then fused GEMM+LN (in-place h)
  aggA_k<<<MTOT/128, 256, 0, stream>>>(h, a);
  layerB_k<<<NPB, 512, 0, stream>>>(h, a, Wt + 32768, gb + 128, lg + 128, lb + 128);
  aggA_k<<<MTOT/128, 256, 0, stream>>>(h, a);
  layerB_k<<<NPB, 512, 0, stream>>>(h, a, Wt + 65536, gb + 256, lg + 256, lb + 256);
  aggA_k<<<MTOT/128, 256, 0, stream>>>(h, a);
  layerB_k<<<NPB, 512, 0, stream>>>(h, a, Wt + 98304, gb + 384, lg + 384, lb + 384);

  mean1_k<<<NB*8, 256, 0, stream>>>(h, partial);
  mean2_k<<<64, 256, 0, stream>>>(partial, gr);
  head1_k<<<64, 256, 0, stream>>>(gr, W1, b1, hid);
  head2_k<<<1, 256, 0, stream>>>(hid, W2, b2, out);
}

// Round 9
// 497.909 us; speedup vs baseline: 1.1001x; 1.1001x over previous
//
#include <hip/hip_runtime.h>

typedef unsigned short u16;
typedef unsigned int   u32;
typedef __attribute__((ext_vector_type(8))) short short8;
typedef __attribute__((ext_vector_type(4))) float f32x4;

#define NN   2024
#define NB   128
#define HID  128
#define MTOT (NN*NB)      // 259072
#define MT   128
#define NBLK (MTOT/MT)    // 2024 = 8*253

__device__ __forceinline__ float bflo(u32 w){ union{u32 u; float f;}c; c.u=w<<16;        return c.f; }
__device__ __forceinline__ float bfhi(u32 w){ union{u32 u; float f;}c; c.u=w&0xffff0000u; return c.f; }
__device__ __forceinline__ float bf2f(u16 h){ union{u32 u; float f;}c; c.u=((u32)h)<<16; return c.f; }
__device__ __forceinline__ u16 f2bf(float f){ union{float f; u32 u;}c; c.f=f; return (u16)((c.u+0x7fffu+((c.u>>16)&1u))>>16); }
__device__ __forceinline__ u32 cvtpk(float lo, float hi){
  u32 r; asm("v_cvt_pk_bf16_f32 %0, %1, %2" : "=v"(r) : "v"(lo), "v"(hi)); return r;
}
__device__ __forceinline__ f32x4 mfma16(short8 a, short8 b, f32x4 c){
  return __builtin_amdgcn_mfma_f32_16x16x32_bf16(a,b,c,0,0,0);
}
__device__ __forceinline__ void glds16(const void* g, void* l){
  __builtin_amdgcn_global_load_lds((const __attribute__((address_space(1))) void*)g,
                                   (__attribute__((address_space(3))) void*)l, 16, 0, 0);
}
__device__ __forceinline__ u32 agg1(u32 a, u32 b, u32 c, u32 d,
                                    float w0, float w1, float w2, float w3){
  float lo = w0*bflo(a); lo=fmaf(w1,bflo(b),lo); lo=fmaf(w2,bflo(c),lo); lo=fmaf(w3,bflo(d),lo);
  float hi = w0*bfhi(a); hi=fmaf(w1,bfhi(b),hi); hi=fmaf(w2,bfhi(c),hi); hi=fmaf(w3,bfhi(d),hi);
  return cvtpk(lo, hi);
}

// ===== pass A: a[r] = weighted-mean of neighbor h rows. Canonically coalesced:
// thread = (row, 16B chunk); 16 consecutive lanes cover one 256B row contiguously.
__global__ __launch_bounds__(256, 8)
void aggA_k(const u16* __restrict__ h, u16* __restrict__ a)
{
  const int idx = blockIdx.x*256 + threadIdx.x;   // MTOT*16 total
  const int row = idx >> 4;
  const int c   = idx & 15;                       // 16B chunk within row
  const int nd = row % NN;
  const int v0 = (nd >= 45), v1 = (nd <= NN-46), v2 = (nd >= 1), v3 = (nd <= NN-2);
  const int cnt = v0+v1+v2+v3;
  const float inv = (cnt==4) ? 0.25f : ((cnt==3) ? (1.f/3.f) : 0.5f);
  const float w0 = v0?inv:0.f, w1 = v1?inv:0.f, w2 = v2?inv:0.f, w3 = v3?inv:0.f;

  const u16* p0 = h + (u32)(v0 ? row-45 : row)*128u + c*8;
  const u16* p1 = h + (u32)(v1 ? row+45 : row)*128u + c*8;
  const u16* p2 = h + (u32)(v2 ? row-1  : row)*128u + c*8;
  const u16* p3 = h + (u32)(v3 ? row+1  : row)*128u + c*8;

  union{ uint4 v; u32 u[4]; } b0, b1, b2, b3, o;
  b0.v = *(const uint4*)p0;
  b1.v = *(const uint4*)p1;
  b2.v = *(const uint4*)p2;
  b3.v = *(const uint4*)p3;
#pragma unroll
  for (int p = 0; p < 4; ++p)
    o.u[p] = agg1(b0.u[p], b1.u[p], b2.u[p], b3.u[p], w0, w1, w2, w3);
  *(uint4*)(a + (u32)row*128u + c*8) = o.v;
}

// ===== pass B: h'[r] = LN(relu(h[r]@W0 + a[r]@W1 + b))*g + beta, IN PLACE =====
// 2024 blocks x 512 thr (8 waves = 2 row-groups x 4 col-groups), 128 rows/block.
// W (64KB, both chunks) in LDS; unified 8-chunk K-loop with EXPLICIT register
// double-buffering of the per-lane A-stream (self then agg). No loop barriers.
__global__ __launch_bounds__(512, 4)
void layerL_k(u16* __restrict__ h, const u16* __restrict__ a,
              const u16* __restrict__ Wt, const float* __restrict__ bias,
              const float* __restrict__ lng, const float* __restrict__ lnb)
{
  __shared__ __align__(16) char Wl[65536];      // [128 col][256 k]*2B, 512B rows, XOR-swz
  __shared__ __align__(16) float2 red[128][4];  // 4KB LN partials
  const int t  = threadIdx.x;
  const int l  = t & 63;
  const int wv = t >> 6;
  const int wr = wv >> 2;        // 0..1 : 64-row group
  const int wc = wv & 3;         // 0..3 : 32-col group
  const int cB = l & 15, rg = l >> 4;

  // bijective XCD swizzle: 2024 = 8*253
  const int orig = blockIdx.x;
  const int m0 = ((orig & 7)*253 + (orig >> 3)) * MT;

  // ---- stage W once via global_load_lds (R8-proven verbatim) ----
#pragma unroll
  for (int i = 0; i < 8; ++i){
    const int slot = wv*8 + i;                  // 64 slots x 1KB
    const int col  = slot*2 + (l >> 5);
    const u32 kb   = ((u32)((l & 31)*16)) ^ ((u32)((col & 7) << 4));
    glds16((const char*)Wt + (u32)col*512 + kb, Wl + (u32)slot*1024);
  }

  f32x4 acc[4][2];
#pragma unroll
  for (int m = 0; m < 4; ++m){ acc[m][0] = (f32x4){0,0,0,0}; acc[m][1] = (f32x4){0,0,0,0}; }

  const u32 kswz = ((u32)(cB & 7)) << 4;
  const char* wp0 = Wl + (u32)(32*wc + cB)*512;        // j=0 col
  const char* wp1 = Wl + (u32)(32*wc + 16 + cB)*512;   // j=1 col
  const char* sp = (const char*)h + (u32)(m0 + 64*wr + cB)*256u + (u32)rg*16u;
  const char* ap = (const char*)a + (u32)(m0 + 64*wr + cB)*256u + (u32)rg*16u;

  __syncthreads();   // B1: W resident

  // ---- unified 8-chunk K-loop, explicit A double-buffer ----
  short8 sA[4], sN[4];
#pragma unroll
  for (int m = 0; m < 4; ++m) sA[m] = *(const short8*)(sp + m*4096);
#pragma unroll
  for (int kc = 0; kc < 8; ++kc){
    // prefetch next chunk's A-frags (self: kc 0..3 ; agg: kc 4..7)
    if (kc < 7){
      const int kn = kc + 1;
      const char* base = (kn < 4) ? sp : ap;
      const u32 off = (u32)(kn & 3)*64u;
#pragma unroll
      for (int m = 0; m < 4; ++m) sN[m] = *(const short8*)(base + m*4096 + off);
    }
    // W fragments for this chunk (LDS)
    const u32 kx = ((u32)kc*64u + (u32)rg*16u) ^ kswz;
    short8 wf0 = *(const short8*)(wp0 + kx);
    short8 wf1 = *(const short8*)(wp1 + kx);
#pragma unroll
    for (int m = 0; m < 4; ++m){
      acc[m][0] = mfma16(sA[m], wf0, acc[m][0]);
      acc[m][1] = mfma16(sA[m], wf1, acc[m][1]);
    }
#pragma unroll
    for (int m = 0; m < 4; ++m) sA[m] = sN[m];
  }

  // ---- epilogue: bias + relu + LN partials ----
  float b2c[2], g2c[2], bt2c[2];
#pragma unroll
  for (int j = 0; j < 2; ++j){
    const int col = 32*wc + 16*j + cB;
    b2c[j] = bias[col]; g2c[j] = lng[col]; bt2c[j] = lnb[col];
  }
#pragma unroll
  for (int m = 0; m < 4; ++m){
#pragma unroll
    for (int rr = 0; rr < 4; ++rr){
      float y0 = fmaxf(acc[m][0][rr] + b2c[0], 0.f);
      float y1 = fmaxf(acc[m][1][rr] + b2c[1], 0.f);
      acc[m][0][rr] = y0; acc[m][1][rr] = y1;
      float s1 = y0 + y1;
      float s2 = fmaf(y0, y0, y1*y1);
      s1 += __shfl_xor(s1,1); s2 += __shfl_xor(s2,1);
      s1 += __shfl_xor(s1,2); s2 += __shfl_xor(s2,2);
      s1 += __shfl_xor(s1,4); s2 += __shfl_xor(s2,4);
      s1 += __shfl_xor(s1,8); s2 += __shfl_xor(s2,8);
      if (cB == 0) red[64*wr + 16*m + 4*rg + rr][wc] = make_float2(s1, s2);
    }
  }
  __syncthreads();   // B2: red ready; all Wl reads done -> reuse as transpose buf

  char* trB = Wl;    // 128 rows x 256B
#pragma unroll
  for (int m = 0; m < 4; ++m){
#pragma unroll
    for (int rr = 0; rr < 4; ++rr){
      const int rl = 64*wr + 16*m + 4*rg + rr;
      const float4 A = *(const float4*)&red[rl][0];
      const float4 B = *(const float4*)&red[rl][2];
      const float s1 = A.x + A.z + B.x + B.z;
      const float s2 = A.y + A.w + B.y + B.w;
      const float mu = s1 * (1.f/128.f);
      const float va = s2 * (1.f/128.f) - mu*mu;
      const float rs = rsqrtf(va + 1e-5f);
      const u32 sw = ((u32)(rl & 7)) << 4;
      char* rowp = trB + (u32)rl*256;
#pragma unroll
      for (int j = 0; j < 2; ++j){
        const float y = fmaf((acc[m][j][rr]-mu)*rs, g2c[j], bt2c[j]);
        const float p = __shfl_xor(y, 1);
        const u32 pk = (cB & 1) ? cvtpk(p, y) : cvtpk(y, p);
        const u32 off = ((u32)(64*wc + 32*j + 2*(cB & ~1))) ^ sw;
        *(u32*)(rowp + off) = pk;
      }
    }
  }
  __syncthreads();   // B3: transpose ready

  // ---- coalesced in-place store: 4 lanes cover one row (64B each) ----
  const int r = t >> 2, q = t & 3;
  const u32 sw2 = ((u32)(r & 7)) << 4;
  u16* dst = h + (size_t)(m0 + r)*HID + q*32;
  const char* srow = trB + (u32)r*256;
#pragma unroll
  for (int i = 0; i < 4; ++i)
    *(short8*)(dst + i*8) = *(const short8*)(srow + (((u32)(q*64 + i*16)) ^ sw2));
}

// ===== layer 1 (rank-1 shortcut) =====
__global__ __launch_bounds__(256, 4)
void l1_k(const float* __restrict__ x, const float* __restrict__ uvec,
          const float* __restrict__ lng, const float* __restrict__ lnb,
          u16* __restrict__ hout)
{
  __shared__ float su[384];
  __shared__ float sg[128], sb[128];
  const int t = threadIdx.x;
  const int m0 = ((blockIdx.x & 7)*253 + (blockIdx.x >> 3)) * 128;
  for (int i = t; i < 384; i += 256) su[i] = uvec[i];
  if (t < 128){ sg[t] = lng[t]; sb[t] = lnb[t]; }
  __syncthreads();

  const int r = t >> 1, hf = t & 1;
  const int grow = m0 + r;
  const int nd = grow % NN;
  const int v0 = (nd >= 45), v1 = (nd <= NN-46), v2 = (nd >= 1), v3 = (nd <= NN-2);
  const int cnt = v0+v1+v2+v3;
  const float inv = (cnt==4) ? 0.25f : ((cnt==3) ? (1.f/3.f) : 0.5f);
  const float xv = x[grow];
  float mx = 0.f;
  if (v0) mx += x[grow-45];
  if (v1) mx += x[grow+45];
  if (v2) mx += x[grow-1];
  if (v3) mx += x[grow+1];
  mx *= inv;

  const int fb = hf*64;
  float4 yv[16];
  float s1 = 0.f, s2 = 0.f;
#pragma unroll
  for (int i = 0; i < 16; ++i){
    const float4 aa = *(const float4*)(su + fb + i*4);
    const float4 bb = *(const float4*)(su + 128 + fb + i*4);
    const float4 cc = *(const float4*)(su + 256 + fb + i*4);
    float4 y;
    y.x = fmaxf(fmaf(xv, aa.x, fmaf(mx, bb.x, cc.x)), 0.f);
    y.y = fmaxf(fmaf(xv, aa.y, fmaf(mx, bb.y, cc.y)), 0.f);
    y.z = fmaxf(fmaf(xv, aa.z, fmaf(mx, bb.z, cc.z)), 0.f);
    y.w = fmaxf(fmaf(xv, aa.w, fmaf(mx, bb.w, cc.w)), 0.f);
    yv[i] = y;
    s1 += y.x + y.y + y.z + y.w;
    s2 = fmaf(y.x,y.x, fmaf(y.y,y.y, fmaf(y.z,y.z, fmaf(y.w,y.w, s2))));
  }
  s1 += __shfl_xor(s1, 1);
  s2 += __shfl_xor(s2, 1);
  const float muv = s1 * (1.f/128.f);
  const float var = s2 * (1.f/128.f) - muv*muv;
  const float rsv = rsqrtf(var + 1e-5f);

  u16* dst = hout + (size_t)grow*HID + fb;
#pragma unroll
  for (int i = 0; i < 8; ++i){
    const float4 ya = yv[2*i], yb = yv[2*i+1];
    const float4 ga = *(const float4*)(sg + fb + i*8);
    const float4 gb2 = *(const float4*)(sg + fb + i*8 + 4);
    const float4 ba = *(const float4*)(sb + fb + i*8);
    const float4 bb = *(const float4*)(sb + fb + i*8 + 4);
    u32 o0 = cvtpk(fmaf((ya.x-muv)*rsv, ga.x, ba.x), fmaf((ya.y-muv)*rsv, ga.y, ba.y));
    u32 o1 = cvtpk(fmaf((ya.z-muv)*rsv, ga.z, ba.z), fmaf((ya.w-muv)*rsv, ga.w, ba.w));
    u32 o2 = cvtpk(fmaf((yb.x-muv)*rsv, gb2.x, bb.x), fmaf((yb.y-muv)*rsv, gb2.y, bb.y));
    u32 o3 = cvtpk(fmaf((yb.z-muv)*rsv, gb2.z, bb.z), fmaf((yb.w-muv)*rsv, gb2.w, bb.w));
    uint4 pk = make_uint4(o0, o1, o2, o3);
    *(uint4*)(dst + i*8) = pk;
  }
}

// Transpose gnn_W [4][256k][128j] f32 -> Wt [4][128j][256k] bf16
__global__ void prep_k(const float* __restrict__ gw, u16* __restrict__ Wt){
  const int idx = blockIdx.x*256 + threadIdx.x;   // 131072
  const int lay = idx >> 15;
  const int r   = idx & 32767;
  const int j   = r >> 8;
  const int k   = r & 255;
  Wt[idx] = f2bf(gw[lay*32768 + k*128 + j]);
}

// u0 = We@W0_l0, u1 = We@W1_l0, c = be@(W0+W1) + b_l0
__global__ void prep2_k(const float* __restrict__ We, const float* __restrict__ be,
                        const float* __restrict__ gW, const float* __restrict__ gb,
                        float* __restrict__ uvec){
  const int f = threadIdx.x;  // 128
  float u0 = 0.f, u1 = 0.f, c = 0.f;
  for (int k = 0; k < 128; ++k){
    const float a = gW[k*128 + f];
    const float b = gW[(128+k)*128 + f];
    u0 = fmaf(We[k], a, u0);
    u1 = fmaf(We[k], b, u1);
    c  = fmaf(be[k], a + b, c);
  }
  uvec[f] = u0; uvec[128+f] = u1; uvec[256+f] = c + gb[f];
}

// ===== graph mean + heads =====
__global__ void mean1_k(const u16* __restrict__ h, float* __restrict__ partial){
  __shared__ float red[16][16][8];
  const int blk = blockIdx.x;                     // 1024 = 128 b x 8 s
  const int b = blk >> 3, s = blk & 7;
  const int t = threadIdx.x;
  const int cg = t & 15, q = t >> 4;
  const int nbeg = s*253, nend = nbeg + 253;
  float a[8] = {0.f,0.f,0.f,0.f,0.f,0.f,0.f,0.f};
  const u16* hb = h + (size_t)b * NN * HID;
  for (int n = nbeg + q; n < nend; n += 16){
    short8 v = *(const short8*)(hb + (size_t)n*HID + cg*8);
#pragma unroll
    for (int i = 0; i < 8; ++i) a[i] += bf2f((u16)v[i]);
  }
#pragma unroll
  for (int i = 0; i < 8; ++i) red[q][cg][i] = a[i];
  __syncthreads();
  if (t < 128){
    const int cc = t >> 3, i = t & 7;
    float v = 0.f;
#pragma unroll
    for (int qq = 0; qq < 16; ++qq) v += red[qq][cc][i];
    partial[((size_t)b*8 + s)*128 + t] = v;
  }
}

__global__ void mean2_k(const float* __restrict__ partial, float* __restrict__ gr){
  const int idx = blockIdx.x*256 + threadIdx.x;   // 16384
  const int b = idx >> 7, c = idx & 127;
  float a = 0.f;
#pragma unroll
  for (int s = 0; s < 8; ++s) a += partial[((size_t)b*8 + s)*128 + c];
  gr[idx] = a * (1.0f / 2024.0f);
}

__global__ void head1_k(const float* __restrict__ gr, const float* __restrict__ W1,
                        const float* __restrict__ b1, float* __restrict__ hid){
  const int idx = blockIdx.x*256 + threadIdx.x;   // 16384
  const int b = idx >> 7, j = idx & 127;
  const float* g = gr + b*128;
  float a = b1[j];
  for (int k = 0; k < 128; ++k) a = fmaf(g[k], W1[k*128 + j], a);
  hid[idx] = fmaxf(a, 0.f);
}

__global__ void head2_k(const float* __restrict__ hid, const float* __restrict__ W2,
                        const float* __restrict__ b2, float* __restrict__ out){
  const int t = threadIdx.x;                      // 256 = 128 b x 2 o
  const int b = t >> 1, o = t & 1;
  const float* hh = hid + b*128;
  float a = b2[o];
  for (int k = 0; k < 128; ++k) a = fmaf(hh[k], W2[k*2 + o], a);
  out[t] = a;
}

extern "C" void kernel_launch(void* const* d_in, const int* in_sizes, int n_in,
                              void* d_out, int out_size, void* d_ws, size_t ws_size,
                              hipStream_t stream){
  const float* x  = (const float*)d_in[0];
  const float* We = (const float*)d_in[1];
  const float* be = (const float*)d_in[2];
  const float* gW = (const float*)d_in[3];
  const float* gb = (const float*)d_in[4];
  const float* lg = (const float*)d_in[5];
  const float* lb = (const float*)d_in[6];
  const float* W1 = (const float*)d_in[7];
  const float* b1 = (const float*)d_in[8];
  const float* W2 = (const float*)d_in[9];
  const float* b2 = (const float*)d_in[10];
  float* out = (float*)d_out;

  char* w = (char*)d_ws;
  const size_t HB = (size_t)MTOT * HID * 2;       // 66,322,432 B
  u16*   h    = (u16*)w;                          // in-place h across layers
  u16*   a    = (u16*)(w + HB);                   // agg buffer (reused per layer)
  u16*   Wt   = (u16*)(w + 2*HB);                 // 262,144 B
  float* uvec = (float*)(w + 2*HB + 262144);      // 4,096 B slot
  float* gr   = (float*)(w + 2*HB + 266240);      // 65,536 B
  float* hid  = (float*)(w + 2*HB + 331776);      // 65,536 B
  float* partial = (float*)(w + HB);              // overlays a (dead after last layer)

  prep2_k<<<1, 128, 0, stream>>>(We, be, gW, gb, uvec);
  prep_k<<<512, 256, 0, stream>>>(gW, Wt);
  l1_k<<<MTOT/128, 256, 0, stream>>>(x, uvec, lg, lb, h);

  // layers 2..4: coalesced agg then pipelined GEMM+LN (in-place h)
  aggA_k<<<MTOT*16/256, 256, 0, stream>>>(h, a);
  layerL_k<<<NBLK, 512, 0, stream>>>(h, a, Wt + 32768, gb + 128, lg + 128, lb + 128);
  aggA_k<<<MTOT*16/256, 256, 0, stream>>>(h, a);
  layerL_k<<<NBLK, 512, 0, stream>>>(h, a, Wt + 65536, gb + 256, lg + 256, lb + 256);
  aggA_k<<<MTOT*16/256, 256, 0, stream>>>(h, a);
  layerL_k<<<NBLK, 512, 0, stream>>>(h, a, Wt + 98304, gb + 384, lg + 384, lb + 384);

  mean1_k<<<NB*8, 256, 0, stream>>>(h, partial);
  mean2_k<<<64, 256, 0, stream>>>(partial, gr);
  head1_k<<<64, 256, 0, stream>>>(gr, W1, b1, hid);
  head2_k<<<1, 256, 0, stream>>>(hid, W2, b2, out);
}